// Round 10
// baseline (413.841 us; speedup 1.0000x reference)
//
#include <hip/hip_runtime.h>
#include <hip/hip_bf16.h>

#define K_DIM 16384
#define M_DIM 512
#define N_DIM 2560
#define BN 32
#define BK 64
#define KSPLIT 8
#define KCH (K_DIM / KSPLIT)   // 2048
#define NT (KCH / BK)          // 32

typedef float f32x4 __attribute__((ext_vector_type(4)));
typedef __bf16 bf16x8 __attribute__((ext_vector_type(8)));

__device__ __forceinline__ unsigned short f2bf(float f){
  union { float f; unsigned u; } v; v.f = f;
  unsigned r = v.u + 0x7FFFu + ((v.u >> 16) & 1u);
  return (unsigned short)(r >> 16);
}
__device__ __forceinline__ unsigned bfpack2(float lo, float hi){
  return (unsigned)f2bf(lo) | ((unsigned)f2bf(hi) << 16);
}

// K1: w_mean[c] = mean_f conv1_w[f][c]; b_mean = mean(conv1_b)
__global__ __launch_bounds__(256)
void prep_kernel(const float* __restrict__ conv1_w, const float* __restrict__ conv1_b,
                 float* __restrict__ w_mean, float* __restrict__ b_mean)
{
  int c = blockIdx.x * 256 + threadIdx.x;
  if (c < K_DIM){
    float s = 0.f;
    #pragma unroll
    for (int f = 0; f < 10; ++f) s += conv1_w[f * K_DIM + c];
    w_mean[c] = s * 0.1f;
  }
  if (blockIdx.x == 0 && threadIdx.x == 0){
    float s = 0.f;
    #pragma unroll
    for (int f = 0; f < 10; ++f) s += conv1_b[f];
    *b_mean = s * 0.1f;
  }
}

// K2: pooled[row] = x[row,:].w_mean + b_mean  AND  xbf[row,:] = bf16(x[row,:])
__global__ __launch_bounds__(256)
void pooled_kernel(const float* __restrict__ X, const float* __restrict__ w_mean,
                   const float* __restrict__ b_mean, float* __restrict__ pooled,
                   unsigned short* __restrict__ xbf)
{
  const int row = blockIdx.x;
  const int tid = threadIdx.x;
  const float* xr = X + (size_t)row * K_DIM;
  unsigned short* xb = xbf + (size_t)row * K_DIM;
  float s = 0.f;
  #pragma unroll 2
  for (int i = 0; i < 8; ++i){
    int idx = (tid + 256 * i) * 8;
    float4 a0 = *(const float4*)(xr + idx);
    float4 a1 = *(const float4*)(xr + idx + 4);
    float4 w0 = *(const float4*)(w_mean + idx);
    float4 w1 = *(const float4*)(w_mean + idx + 4);
    s += a0.x*w0.x + a0.y*w0.y + a0.z*w0.z + a0.w*w0.w
       + a1.x*w1.x + a1.y*w1.y + a1.z*w1.z + a1.w*w1.w;
    uint4 p;
    p.x = bfpack2(a0.x, a0.y); p.y = bfpack2(a0.z, a0.w);
    p.z = bfpack2(a1.x, a1.y); p.w = bfpack2(a1.z, a1.w);
    *(uint4*)(xb + idx) = p;
  }
  #pragma unroll
  for (int off = 32; off; off >>= 1) s += __shfl_down(s, off);
  __shared__ float red[4];
  if ((tid & 63) == 0) red[tid >> 6] = s;
  __syncthreads();
  if (tid == 0) pooled[row] = red[0] + red[1] + red[2] + red[3] + *b_mean;
}

// K3: gates
__global__ __launch_bounds__(512)
void gates_kernel(const float* __restrict__ pooled, const float* __restrict__ fw,
                  const float* __restrict__ fb, const float* __restrict__ aw,
                  float* __restrict__ gates)
{
  __shared__ float ps[512];
  int tid = threadIdx.x;
  ps[tid] = pooled[tid];
  __syncthreads();
  int b = tid >> 5, s = tid & 31;
  float z = fb[s];
  #pragma unroll
  for (int t = 0; t < 32; ++t) z += ps[b * 32 + t] * fw[s * 32 + t];
  float mx = z;
  #pragma unroll
  for (int off = 16; off; off >>= 1) mx = fmaxf(mx, __shfl_xor(mx, off));
  float e = expf(z - mx);
  float sum = e;
  #pragma unroll
  for (int off = 16; off; off >>= 1) sum += __shfl_xor(sum, off);
  float sm = e / sum;
  float relu = z > 0.f ? z : 0.f;
  float sig = 1.f / (1.f + expf(-z));
  gates[tid] = aw[0] * relu + aw[1] * sig + aw[2] * sm;
}

// K4 v9: BM=512 (full M -> W read EXACTLY once), BN=32, BK=64, KSPLIT=8,
// grid 640 (2.5 blocks/CU; launch_bounds(512,4) -> >=2 resident). NO A-LDS:
// A bf16 fragments loaded straight from the L2-resident xbf kz-slice into regs.
// LDS = B only, 2x4KB double-buffered; per step ONE s_barrier with lgkm-only
// drain (B global prefetch 2-deep rides across barriers; waited at its use).
__global__ __launch_bounds__(512, 4)
void gemm_kernel(const unsigned short* __restrict__ Abf, const float* __restrict__ W,
                 float* __restrict__ outp, int mode)
{
  __shared__ __align__(16) char smem[2][4096];

  const int tid  = threadIdx.x;
  const int lane = tid & 63;
  const int wv   = tid >> 6;          // 8 waves
  const int wm   = wv * 64;           // wave tile 64m x 32n

  const int id = blockIdx.x;
  const int kz = id & 7;              // XCD-pinned K-slice
  const int n0 = (id >> 3) * BN;
  const int kbase = kz * KCH;

  f32x4 acc[4][2] = {};

  // B staging: thread -> n-row = tid>>4 (0..31), k-chunk = (tid&15)*4 fp32
  const int brow = tid >> 4;
  const int bc4  = tid & 15;
  const float* bsrc = W + (size_t)(n0 + brow) * K_DIM + kbase + bc4 * 4;
  const int boff = brow * 128 + ((bc4 * 8) ^ ((brow & 7) << 4));

  // A direct-load base: row = wm + (lane&15) (+i*16), k = kbase + (lane>>4)*8 (+t*64+kk*32)
  const unsigned short* abase = Abf + (size_t)(wm + (lane & 15)) * K_DIM
                                + kbase + (lane >> 4) * 8;

  auto writeB = [&](int buf, const float4& r){
    uint2 u; u.x = bfpack2(r.x, r.y); u.y = bfpack2(r.z, r.w);
    *(uint2*)(smem[buf] + boff) = u;
  };

  float4 rbP;                          // 2-ahead B prefetch register
  { float4 r0 = *(const float4*)(bsrc); writeB(0, r0); }
  rbP = *(const float4*)(bsrc + BK);
  __syncthreads();

  for (int t = 0; t < NT; ++t){
    if (t + 1 < NT) writeB((t + 1) & 1, rbP);            // overlaps compute(t)
    if (t + 2 < NT) rbP = *(const float4*)(bsrc + (t + 2) * BK);
    const char* Bb = smem[t & 1];
    const unsigned short* ab = abase + t * BK;
    #pragma unroll
    for (int kk = 0; kk < 2; ++kk){
      bf16x8 af[4], bfv[2];
      #pragma unroll
      for (int i = 0; i < 4; ++i)
        af[i] = *(const bf16x8*)(ab + (size_t)i * 16 * K_DIM + kk * 32);
      #pragma unroll
      for (int j = 0; j < 2; ++j){
        int row = j * 16 + (lane & 15);
        bfv[j] = *(const bf16x8*)(Bb + row * 128
                    + ((kk * 64 + (lane >> 4) * 16) ^ ((row & 7) << 4)));
      }
      #pragma unroll
      for (int i = 0; i < 4; ++i)
        #pragma unroll
        for (int j = 0; j < 2; ++j)
          acc[i][j] = __builtin_amdgcn_mfma_f32_16x16x32_bf16(af[i], bfv[j], acc[i][j], 0, 0, 0);
    }
    // lgkm-only drain (ds_write of B(t+1) + ds_reads done); vm prefetch stays in flight
    asm volatile("s_waitcnt lgkmcnt(0)" ::: "memory");
    __builtin_amdgcn_s_barrier();
  }

  if (mode == 0){
    float* P = outp + (size_t)kz * M_DIM * N_DIM;
    #pragma unroll
    for (int i = 0; i < 4; ++i){
      int rbase = wm + i * 16 + (lane >> 4) * 4;
      #pragma unroll
      for (int j = 0; j < 2; ++j){
        int col = n0 + j * 16 + (lane & 15);
        #pragma unroll
        for (int r2 = 0; r2 < 4; ++r2)
          P[(size_t)(rbase + r2) * N_DIM + col] = acc[i][j][r2];
      }
    }
  } else {
    #pragma unroll
    for (int i = 0; i < 4; ++i){
      int rbase = wm + i * 16 + (lane >> 4) * 4;
      #pragma unroll
      for (int j = 0; j < 2; ++j){
        int col = n0 + j * 16 + (lane & 15);
        #pragma unroll
        for (int r2 = 0; r2 < 4; ++r2)
          atomicAdd(&outp[(size_t)(rbase + r2) * N_DIM + col], acc[i][j][r2]);
      }
    }
  }
}

// PROBE 1: W-streaming path only (identical mapping/grid as gemm). Measures the
// read-once W fp32 path. Result folded + stored to sink (no DCE).
__global__ __launch_bounds__(512, 4)
void probe_streamW(const float* __restrict__ W, float* __restrict__ sink)
{
  const int tid = threadIdx.x;
  const int id = blockIdx.x;
  const int kz = id & 7;
  const int n0 = (id >> 3) * BN;
  const int kbase = kz * KCH;
  const int brow = tid >> 4;
  const int bc4  = tid & 15;
  const float* bsrc = W + (size_t)(n0 + brow) * K_DIM + kbase + bc4 * 4;
  float4 s = {0.f, 0.f, 0.f, 0.f};
  for (int t = 0; t < NT; ++t){
    float4 r = *(const float4*)(bsrc + t * BK);
    s.x += r.x; s.y += r.y; s.z += r.z; s.w += r.w;
  }
  sink[(size_t)id * 512 + tid] = s.x + s.y + s.z + s.w;
}

// PROBE 2: A-load + MFMA path only (static LDS B written once; no per-step
// staging/barriers). Measures compute-path ceiling at same grid/occupancy.
__global__ __launch_bounds__(512, 4)
void probe_mfma(const unsigned short* __restrict__ Abf, float* __restrict__ sink)
{
  __shared__ __align__(16) char bs[4096];
  const int tid  = threadIdx.x;
  const int lane = tid & 63;
  const int wv   = tid >> 6;
  const int wm   = wv * 64;
  const int id = blockIdx.x;
  const int kz = id & 7;
  const int kbase = kz * KCH;

  // fill static B from Abf bits (content irrelevant)
  *(uint2*)(bs + tid * 8) = *(const uint2*)(Abf + tid * 4);
  __syncthreads();

  f32x4 acc[4][2] = {};
  const unsigned short* abase = Abf + (size_t)(wm + (lane & 15)) * K_DIM
                                + kbase + (lane >> 4) * 8;
  for (int t = 0; t < NT; ++t){
    const unsigned short* ab = abase + t * BK;
    #pragma unroll
    for (int kk = 0; kk < 2; ++kk){
      bf16x8 af[4], bfv[2];
      #pragma unroll
      for (int i = 0; i < 4; ++i)
        af[i] = *(const bf16x8*)(ab + (size_t)i * 16 * K_DIM + kk * 32);
      #pragma unroll
      for (int j = 0; j < 2; ++j){
        int row = j * 16 + (lane & 15);
        bfv[j] = *(const bf16x8*)(bs + row * 128
                    + ((kk * 64 + (lane >> 4) * 16) ^ ((row & 7) << 4)));
      }
      #pragma unroll
      for (int i = 0; i < 4; ++i)
        #pragma unroll
        for (int j = 0; j < 2; ++j)
          acc[i][j] = __builtin_amdgcn_mfma_f32_16x16x32_bf16(af[i], bfv[j], acc[i][j], 0, 0, 0);
    }
  }
  float s = 0.f;
  #pragma unroll
  for (int i = 0; i < 4; ++i)
    #pragma unroll
    for (int j = 0; j < 2; ++j)
      s += acc[i][j][0] + acc[i][j][1] + acc[i][j][2] + acc[i][j][3];
  sink[(size_t)id * 512 + tid] = s;
}

// K5a: out[m,n] = gates[m] * (sum_z partial[z,m,n] + bias[n])
__global__ __launch_bounds__(256)
void reduce_kernel(const float* __restrict__ part, const float* __restrict__ gates,
                   const float* __restrict__ bias, float* __restrict__ out, int ksplit)
{
  int i4 = blockIdx.x * 256 + threadIdx.x;
  if (i4 >= M_DIM * N_DIM / 4) return;
  size_t off = (size_t)i4 * 4;
  int m = (int)(off / N_DIM);
  int n = (int)(off % N_DIM);
  float sx = 0.f, sy = 0.f, sz = 0.f, sw = 0.f;
  for (int z = 0; z < ksplit; ++z){
    float4 p = *(const float4*)(part + (size_t)z * M_DIM * N_DIM + off);
    sx += p.x; sy += p.y; sz += p.z; sw += p.w;
  }
  float4 bv = *(const float4*)(bias + n);
  float g = gates[m];
  float4 o;
  o.x = g * (sx + bv.x); o.y = g * (sy + bv.y);
  o.z = g * (sz + bv.z); o.w = g * (sw + bv.w);
  *(float4*)(out + off) = o;
}

// K5b: finalize after atomic accumulation
__global__ __launch_bounds__(256)
void finalize_kernel(float* __restrict__ out, const float* __restrict__ gates,
                     const float* __restrict__ bias)
{
  int i4 = blockIdx.x * 256 + threadIdx.x;
  if (i4 >= M_DIM * N_DIM / 4) return;
  size_t off = (size_t)i4 * 4;
  int m = (int)(off / N_DIM);
  int n = (int)(off % N_DIM);
  float4 o = *(const float4*)(out + off);
  float4 bv = *(const float4*)(bias + n);
  float g = gates[m];
  o.x = g * (o.x + bv.x); o.y = g * (o.y + bv.y);
  o.z = g * (o.z + bv.z); o.w = g * (o.w + bv.w);
  *(float4*)(out + off) = o;
}

extern "C" void kernel_launch(void* const* d_in, const int* in_sizes, int n_in,
                              void* d_out, int out_size, void* d_ws, size_t ws_size,
                              hipStream_t stream)
{
  const float* input   = (const float*)d_in[0];
  const float* aw      = (const float*)d_in[2];
  const float* conv1_w = (const float*)d_in[3];
  const float* conv1_b = (const float*)d_in[4];
  const float* G3_w    = (const float*)d_in[5];
  const float* G3_b    = (const float*)d_in[6];
  const float* ffnn1_w = (const float*)d_in[7];
  const float* ffnn1_b = (const float*)d_in[8];
  float* out = (float*)d_out;

  float* wsf    = (float*)d_ws;
  float* w_mean = wsf;               // 16384 f
  float* pooled = wsf + 16384;       // 512 f
  float* gates  = wsf + 16896;       // 512 f
  float* b_mean = wsf + 17408;       // 64 f pad
  unsigned short* xbf = (unsigned short*)(wsf + 17472);        // 512*16384 bf16 = 16MB
  float* partial = wsf + 17472 + (size_t)M_DIM * K_DIM / 2;    // 8 * 512*2560 f

  const size_t need_det = ((size_t)17472 + (size_t)M_DIM * K_DIM / 2
                           + (size_t)KSPLIT * M_DIM * N_DIM) * 4;   // ~58.8MB

  prep_kernel<<<64, 256, 0, stream>>>(conv1_w, conv1_b, w_mean, b_mean);
  pooled_kernel<<<512, 256, 0, stream>>>(input, w_mean, b_mean, pooled, xbf);
  gates_kernel<<<1, 512, 0, stream>>>(pooled, ffnn1_w, ffnn1_b, aw, gates);

  const int n4 = M_DIM * N_DIM / 4;
  const int grid = (N_DIM / BN) * KSPLIT;   // 80*8 = 640
  if (ws_size >= need_det){
    gemm_kernel<<<grid, 512, 0, stream>>>(xbf, G3_w, partial, 0);
    reduce_kernel<<<(n4 + 255) / 256, 256, 0, stream>>>(partial, gates, G3_b, out, KSPLIT);
    // ---- diagnostic probes (outputs overwrite partial, already consumed) ----
    probe_streamW<<<grid, 512, 0, stream>>>(G3_w, partial);
    probe_mfma<<<grid, 512, 0, stream>>>(xbf, partial + 1024 * 1024);
  } else {
    hipMemsetAsync(d_out, 0, (size_t)out_size * sizeof(float), stream);
    gemm_kernel<<<grid, 512, 0, stream>>>(xbf, G3_w, out, 2);
    finalize_kernel<<<(n4 + 255) / 256, 256, 0, stream>>>(out, gates, G3_b);
  }
}

// Round 11
// 227.801 us; speedup vs baseline: 1.8167x; 1.8167x over previous
//
#include <hip/hip_runtime.h>
#include <hip/hip_bf16.h>

#define K_DIM 16384
#define M_DIM 512
#define N_DIM 2560
#define BM 512
#define BN 64
#define BK 64

typedef float f32x4 __attribute__((ext_vector_type(4)));
typedef __bf16 bf16x8 __attribute__((ext_vector_type(8)));

__device__ __forceinline__ unsigned short f2bf(float f){
  union { float f; unsigned u; } v; v.f = f;
  unsigned r = v.u + 0x7FFFu + ((v.u >> 16) & 1u);
  return (unsigned short)(r >> 16);
}
__device__ __forceinline__ unsigned bfpack2(float lo, float hi){
  return (unsigned)f2bf(lo) | ((unsigned)f2bf(hi) << 16);
}

// K1: w_mean[c] = mean_f conv1_w[f][c]; b_mean = mean(conv1_b)
__global__ __launch_bounds__(256)
void prep_kernel(const float* __restrict__ conv1_w, const float* __restrict__ conv1_b,
                 float* __restrict__ w_mean, float* __restrict__ b_mean)
{
  int c = blockIdx.x * 256 + threadIdx.x;
  if (c < K_DIM){
    float s = 0.f;
    #pragma unroll
    for (int f = 0; f < 10; ++f) s += conv1_w[f * K_DIM + c];
    w_mean[c] = s * 0.1f;
  }
  if (blockIdx.x == 0 && threadIdx.x == 0){
    float s = 0.f;
    #pragma unroll
    for (int f = 0; f < 10; ++f) s += conv1_b[f];
    *b_mean = s * 0.1f;
  }
}

// K2: pooled[row] = x[row,:].w_mean + b_mean  AND  xbf[row,:] = bf16(x[row,:])
__global__ __launch_bounds__(256)
void pooled_kernel(const float* __restrict__ X, const float* __restrict__ w_mean,
                   const float* __restrict__ b_mean, float* __restrict__ pooled,
                   unsigned short* __restrict__ xbf)
{
  const int row = blockIdx.x;
  const int tid = threadIdx.x;
  const float* xr = X + (size_t)row * K_DIM;
  unsigned short* xb = xbf + (size_t)row * K_DIM;
  float s = 0.f;
  #pragma unroll 2
  for (int i = 0; i < 8; ++i){
    int idx = (tid + 256 * i) * 8;
    float4 a0 = *(const float4*)(xr + idx);
    float4 a1 = *(const float4*)(xr + idx + 4);
    float4 w0 = *(const float4*)(w_mean + idx);
    float4 w1 = *(const float4*)(w_mean + idx + 4);
    s += a0.x*w0.x + a0.y*w0.y + a0.z*w0.z + a0.w*w0.w
       + a1.x*w1.x + a1.y*w1.y + a1.z*w1.z + a1.w*w1.w;
    uint4 p;
    p.x = bfpack2(a0.x, a0.y); p.y = bfpack2(a0.z, a0.w);
    p.z = bfpack2(a1.x, a1.y); p.w = bfpack2(a1.z, a1.w);
    *(uint4*)(xb + idx) = p;
  }
  #pragma unroll
  for (int off = 32; off; off >>= 1) s += __shfl_down(s, off);
  __shared__ float red[4];
  if ((tid & 63) == 0) red[tid >> 6] = s;
  __syncthreads();
  if (tid == 0) pooled[row] = red[0] + red[1] + red[2] + red[3] + *b_mean;
}

// K3: gates
__global__ __launch_bounds__(512)
void gates_kernel(const float* __restrict__ pooled, const float* __restrict__ fw,
                  const float* __restrict__ fb, const float* __restrict__ aw,
                  float* __restrict__ gates)
{
  __shared__ float ps[512];
  int tid = threadIdx.x;
  ps[tid] = pooled[tid];
  __syncthreads();
  int b = tid >> 5, s = tid & 31;
  float z = fb[s];
  #pragma unroll
  for (int t = 0; t < 32; ++t) z += ps[b * 32 + t] * fw[s * 32 + t];
  float mx = z;
  #pragma unroll
  for (int off = 16; off; off >>= 1) mx = fmaxf(mx, __shfl_xor(mx, off));
  float e = expf(z - mx);
  float sum = e;
  #pragma unroll
  for (int off = 16; off; off >>= 1) sum += __shfl_xor(sum, off);
  float sm = e / sum;
  float relu = z > 0.f ? z : 0.f;
  float sig = 1.f / (1.f + expf(-z));
  gates[tid] = aw[0] * relu + aw[1] * sig + aw[2] * sm;
}

// K4 v10: CO-RESIDENCY build. BM=512 (W read once), BN=64, BK=64, runtime ksplit.
// 8 waves (512 thr), wave tile 64x64 (acc[4][4] -> AGPRs). LDS = A single 64KB +
// B double 2x8KB = 80KB -> EXACTLY 2 blocks/CU resident; launch_bounds(512,4)
// caps VGPR at 128 so waves fit 4/SIMD. Simple proven 2-barrier loop; the
// per-step gll/drain stall of one block is hidden by the OTHER resident block
// (m97/m114 mechanism). kz = id&(ksplit-1): XCD-pinned xbf slices (L2-resident).
__global__ __launch_bounds__(512, 4)
void gemm_kernel(const unsigned short* __restrict__ Abf, const float* __restrict__ W,
                 float* __restrict__ outp, int ksplit, int kshift, int mode)
{
  __shared__ __align__(16) char smem[81920];   // A 64KB | B[2] 8KB each
  char* Asm = smem;
  char* Bsm0 = smem + 65536;
  char* Bsm1 = smem + 73728;

  const int tid  = threadIdx.x;
  const int lane = tid & 63;
  const int wv   = tid >> 6;
  const int wm   = wv * 64;

  const int id = blockIdx.x;
  const int kz = id & (ksplit - 1);
  const int n0 = (id >> kshift) * BN;
  const int KCH = K_DIM >> kshift;
  const int NT  = KCH / BK;
  const int kbase = kz * KCH;

  f32x4 acc[4][4] = {};

  // A gll: chunk u = j*512 + tid -> row = j*64 + (tid>>3), c8 = tid&7.
  // LDS[row][c8] holds A[row][c8 ^ (row&7)] (pre-swizzled global source).
  const int arow0 = tid >> 3;
  const int ac8   = (tid & 7) ^ (arow0 & 7);
  const unsigned short* asrc = Abf + (size_t)arow0 * K_DIM + ac8 * 8;

  auto stageA = [&](int k0){
    #pragma unroll
    for (int j = 0; j < 8; ++j){
      __builtin_amdgcn_global_load_lds(
        (const __attribute__((address_space(1))) void*)(asrc + (size_t)j * 64 * K_DIM + k0),
        (__attribute__((address_space(3))) void*)(Asm + j * 8192 + tid * 16),
        16, 0, 0);
    }
  };

  // B: row = tid>>3 (0..63), c8 = tid&7 -> 8 fp32 (2 float4) -> 1 uint4 bf16
  const int brow = tid >> 3;
  const int bc8  = tid & 7;
  const float* bsrc = W + (size_t)(n0 + brow) * K_DIM + kbase + bc8 * 8;
  const int boff = brow * 128 + ((bc8 * 16) ^ ((brow & 7) << 4));

  auto loadB = [&](int kt, float4* r){
    const float* p = bsrc + kt * BK;
    r[0] = *(const float4*)p;
    r[1] = *(const float4*)(p + 4);
  };
  auto writeB = [&](int buf, const float4* r){
    uint4 u;
    u.x = bfpack2(r[0].x, r[0].y); u.y = bfpack2(r[0].z, r[0].w);
    u.z = bfpack2(r[1].x, r[1].y); u.w = bfpack2(r[1].z, r[1].w);
    *(uint4*)((buf ? Bsm1 : Bsm0) + boff) = u;
  };

  auto compute = [&](const char* Bb){
    #pragma unroll
    for (int kk = 0; kk < 2; ++kk){
      bf16x8 af[4], bfv[4];
      const int kbyte = kk * 64 + (lane >> 4) * 16;
      #pragma unroll
      for (int i = 0; i < 4; ++i){
        int row = wm + i * 16 + (lane & 15);
        af[i] = *(const bf16x8*)(Asm + row * 128 + (kbyte ^ ((row & 7) << 4)));
      }
      #pragma unroll
      for (int j = 0; j < 4; ++j){
        int rowb = j * 16 + (lane & 15);
        bfv[j] = *(const bf16x8*)(Bb + rowb * 128 + (kbyte ^ ((rowb & 7) << 4)));
      }
      #pragma unroll
      for (int i = 0; i < 4; ++i)
        #pragma unroll
        for (int j = 0; j < 4; ++j)
          acc[i][j] = __builtin_amdgcn_mfma_f32_16x16x32_bf16(af[i], bfv[j], acc[i][j], 0, 0, 0);
    }
  };

  float4 rbA[2], rbB[2];
  // prologue: publish B(0) + A(0); B(1) in rbA
  loadB(0, rbB);
  writeB(0, rbB);
  loadB(1, rbA);
  stageA(kbase);
  __syncthreads();

  // BODY(t): loads B(t+2), computes tile t, stages A(t+1) + writes B(t+1)
  #define BODY(T, RC, RN)                                   \
    do {                                                    \
      if ((T) + 2 < NT) loadB((T) + 2, RN);                 \
      compute(((T) & 1) ? Bsm1 : Bsm0);                     \
      __syncthreads();                                      \
      if ((T) + 1 < NT){                                    \
        stageA(kbase + ((T) + 1) * BK);                     \
        writeB(((T) + 1) & 1, RC);                          \
      }                                                     \
      __syncthreads();                                      \
    } while (0)

  for (int t = 0; t < NT; t += 2){
    BODY(t, rbA, rbB);
    BODY(t + 1, rbB, rbA);
  }
  #undef BODY

  if (mode == 0){
    float* P = outp + (size_t)kz * M_DIM * N_DIM;
    #pragma unroll
    for (int i = 0; i < 4; ++i){
      int rbase = wm + i * 16 + (lane >> 4) * 4;
      #pragma unroll
      for (int j = 0; j < 4; ++j){
        int col = n0 + j * 16 + (lane & 15);
        #pragma unroll
        for (int r2 = 0; r2 < 4; ++r2)
          P[(size_t)(rbase + r2) * N_DIM + col] = acc[i][j][r2];
      }
    }
  } else {
    #pragma unroll
    for (int i = 0; i < 4; ++i){
      int rbase = wm + i * 16 + (lane >> 4) * 4;
      #pragma unroll
      for (int j = 0; j < 4; ++j){
        int col = n0 + j * 16 + (lane & 15);
        #pragma unroll
        for (int r2 = 0; r2 < 4; ++r2)
          atomicAdd(&outp[(size_t)(rbase + r2) * N_DIM + col], acc[i][j][r2]);
      }
    }
  }
}

// K5a: out[m,n] = gates[m] * (sum_z partial[z,m,n] + bias[n])
__global__ __launch_bounds__(256)
void reduce_kernel(const float* __restrict__ part, const float* __restrict__ gates,
                   const float* __restrict__ bias, float* __restrict__ out, int ksplit)
{
  int i4 = blockIdx.x * 256 + threadIdx.x;
  if (i4 >= M_DIM * N_DIM / 4) return;
  size_t off = (size_t)i4 * 4;
  int m = (int)(off / N_DIM);
  int n = (int)(off % N_DIM);
  float sx = 0.f, sy = 0.f, sz = 0.f, sw = 0.f;
  for (int z = 0; z < ksplit; ++z){
    float4 p = *(const float4*)(part + (size_t)z * M_DIM * N_DIM + off);
    sx += p.x; sy += p.y; sz += p.z; sw += p.w;
  }
  float4 bv = *(const float4*)(bias + n);
  float g = gates[m];
  float4 o;
  o.x = g * (sx + bv.x); o.y = g * (sy + bv.y);
  o.z = g * (sz + bv.z); o.w = g * (sw + bv.w);
  *(float4*)(out + off) = o;
}

// K5b: finalize after atomic accumulation
__global__ __launch_bounds__(256)
void finalize_kernel(float* __restrict__ out, const float* __restrict__ gates,
                     const float* __restrict__ bias)
{
  int i4 = blockIdx.x * 256 + threadIdx.x;
  if (i4 >= M_DIM * N_DIM / 4) return;
  size_t off = (size_t)i4 * 4;
  int m = (int)(off / N_DIM);
  int n = (int)(off % N_DIM);
  float4 o = *(const float4*)(out + off);
  float4 bv = *(const float4*)(bias + n);
  float g = gates[m];
  o.x = g * (o.x + bv.x); o.y = g * (o.y + bv.y);
  o.z = g * (o.z + bv.z); o.w = g * (o.w + bv.w);
  *(float4*)(out + off) = o;
}

extern "C" void kernel_launch(void* const* d_in, const int* in_sizes, int n_in,
                              void* d_out, int out_size, void* d_ws, size_t ws_size,
                              hipStream_t stream)
{
  const float* input   = (const float*)d_in[0];
  const float* aw      = (const float*)d_in[2];
  const float* conv1_w = (const float*)d_in[3];
  const float* conv1_b = (const float*)d_in[4];
  const float* G3_w    = (const float*)d_in[5];
  const float* G3_b    = (const float*)d_in[6];
  const float* ffnn1_w = (const float*)d_in[7];
  const float* ffnn1_b = (const float*)d_in[8];
  float* out = (float*)d_out;

  float* wsf    = (float*)d_ws;
  float* w_mean = wsf;               // 16384 f
  float* pooled = wsf + 16384;       // 512 f
  float* gates  = wsf + 16896;       // 512 f
  float* b_mean = wsf + 17408;       // 64 f pad
  unsigned short* xbf = (unsigned short*)(wsf + 17472);        // 16 MB
  float* partial = wsf + 17472 + (size_t)M_DIM * K_DIM / 2;

  const size_t base_f = (size_t)17472 + (size_t)M_DIM * K_DIM / 2;
  const size_t need16 = (base_f + (size_t)16 * M_DIM * N_DIM) * 4;   // ~101 MB
  const size_t need8  = (base_f + (size_t)8  * M_DIM * N_DIM) * 4;   // ~59 MB

  prep_kernel<<<64, 256, 0, stream>>>(conv1_w, conv1_b, w_mean, b_mean);
  pooled_kernel<<<512, 256, 0, stream>>>(input, w_mean, b_mean, pooled, xbf);
  gates_kernel<<<1, 512, 0, stream>>>(pooled, ffnn1_w, ffnn1_b, aw, gates);

  const int n4 = M_DIM * N_DIM / 4;
  if (ws_size >= need16){
    gemm_kernel<<<(N_DIM / BN) * 16, 512, 0, stream>>>(xbf, G3_w, partial, 16, 4, 0);
    reduce_kernel<<<(n4 + 255) / 256, 256, 0, stream>>>(partial, gates, G3_b, out, 16);
  } else if (ws_size >= need8){
    gemm_kernel<<<(N_DIM / BN) * 8, 512, 0, stream>>>(xbf, G3_w, partial, 8, 3, 0);
    reduce_kernel<<<(n4 + 255) / 256, 256, 0, stream>>>(partial, gates, G3_b, out, 8);
  } else {
    hipMemsetAsync(d_out, 0, (size_t)out_size * sizeof(float), stream);
    gemm_kernel<<<(N_DIM / BN) * 16, 512, 0, stream>>>(xbf, G3_w, out, 16, 4, 2);
    finalize_kernel<<<(n4 + 255) / 256, 256, 0, stream>>>(out, gates, G3_b);
  }
}

// Round 12
// 95.870 us; speedup vs baseline: 4.3167x; 2.3761x over previous
//
#include <hip/hip_runtime.h>
#include <hip/hip_bf16.h>

#define K_DIM 16384
#define M_DIM 512
#define N_DIM 2560
#define BM 256
#define BN 160
#define BK 64
#define KSPLIT 8
#define KCH (K_DIM / KSPLIT)   // 2048
#define NT (KCH / BK)          // 32

typedef float f32x4 __attribute__((ext_vector_type(4)));
typedef __bf16 bf16x8 __attribute__((ext_vector_type(8)));

__device__ __forceinline__ unsigned short f2bf(float f){
  union { float f; unsigned u; } v; v.f = f;
  unsigned r = v.u + 0x7FFFu + ((v.u >> 16) & 1u);
  return (unsigned short)(r >> 16);
}
__device__ __forceinline__ unsigned bfpack2(float lo, float hi){
  return (unsigned)f2bf(lo) | ((unsigned)f2bf(hi) << 16);
}

// K1: w_mean[c] = mean_f conv1_w[f][c]; b_mean = mean(conv1_b)
__global__ __launch_bounds__(256)
void prep_kernel(const float* __restrict__ conv1_w, const float* __restrict__ conv1_b,
                 float* __restrict__ w_mean, float* __restrict__ b_mean)
{
  int c = blockIdx.x * 256 + threadIdx.x;
  if (c < K_DIM){
    float s = 0.f;
    #pragma unroll
    for (int f = 0; f < 10; ++f) s += conv1_w[f * K_DIM + c];
    w_mean[c] = s * 0.1f;
  }
  if (blockIdx.x == 0 && threadIdx.x == 0){
    float s = 0.f;
    #pragma unroll
    for (int f = 0; f < 10; ++f) s += conv1_b[f];
    *b_mean = s * 0.1f;
  }
}

// K2: pooled[row] = x[row,:].w_mean + b_mean  AND  xbf[row,:] = bf16(x[row,:])
__global__ __launch_bounds__(256)
void pooled_kernel(const float* __restrict__ X, const float* __restrict__ w_mean,
                   const float* __restrict__ b_mean, float* __restrict__ pooled,
                   unsigned short* __restrict__ xbf)
{
  const int row = blockIdx.x;
  const int tid = threadIdx.x;
  const float* xr = X + (size_t)row * K_DIM;
  unsigned short* xb = xbf + (size_t)row * K_DIM;
  float s = 0.f;
  #pragma unroll 2
  for (int i = 0; i < 8; ++i){
    int idx = (tid + 256 * i) * 8;
    float4 a0 = *(const float4*)(xr + idx);
    float4 a1 = *(const float4*)(xr + idx + 4);
    float4 w0 = *(const float4*)(w_mean + idx);
    float4 w1 = *(const float4*)(w_mean + idx + 4);
    s += a0.x*w0.x + a0.y*w0.y + a0.z*w0.z + a0.w*w0.w
       + a1.x*w1.x + a1.y*w1.y + a1.z*w1.z + a1.w*w1.w;
    uint4 p;
    p.x = bfpack2(a0.x, a0.y); p.y = bfpack2(a0.z, a0.w);
    p.z = bfpack2(a1.x, a1.y); p.w = bfpack2(a1.z, a1.w);
    *(uint4*)(xb + idx) = p;
  }
  #pragma unroll
  for (int off = 32; off; off >>= 1) s += __shfl_down(s, off);
  __shared__ float red[4];
  if ((tid & 63) == 0) red[tid >> 6] = s;
  __syncthreads();
  if (tid == 0) pooled[row] = red[0] + red[1] + red[2] + red[3] + *b_mean;
}

// K3: gates
__global__ __launch_bounds__(512)
void gates_kernel(const float* __restrict__ pooled, const float* __restrict__ fw,
                  const float* __restrict__ fb, const float* __restrict__ aw,
                  float* __restrict__ gates)
{
  __shared__ float ps[512];
  int tid = threadIdx.x;
  ps[tid] = pooled[tid];
  __syncthreads();
  int b = tid >> 5, s = tid & 31;
  float z = fb[s];
  #pragma unroll
  for (int t = 0; t < 32; ++t) z += ps[b * 32 + t] * fw[s * 32 + t];
  float mx = z;
  #pragma unroll
  for (int off = 16; off; off >>= 1) mx = fmaxf(mx, __shfl_xor(mx, off));
  float e = expf(z - mx);
  float sum = e;
  #pragma unroll
  for (int off = 16; off; off >>= 1) sum += __shfl_xor(sum, off);
  float sm = e / sum;
  float relu = z > 0.f ? z : 0.f;
  float sig = 1.f / (1.f + expf(-z));
  gates[tid] = aw[0] * relu + aw[1] * sig + aw[2] * sm;
}

// K4 v11: R6's PROVEN simple 2-barrier structure at FULL coverage.
// BM=256 x BN=160, BK=64, KSPLIT=8 -> grid 2*16*8 = 256 blocks (256 CUs busy).
// 8 waves 4m x 2n, wave tile 64x80 (acc[4][5]). kz=id&7 XCD-pinned; the 2
// m-blocks sharing a W-strip are id-adjacent (same XCD, 2nd read hits L2).
// A: gll double-buffered (2x32KB), pre-swizzled source. B: fp32 reg-staged
// 2-deep, cvt->bf16, LDS double-buffered (2x20KB). Total LDS 104KB.
__global__ __launch_bounds__(512, 2)
void gemm_kernel(const unsigned short* __restrict__ Abf, const float* __restrict__ W,
                 float* __restrict__ outp, int mode)
{
  __shared__ __align__(16) char smem[106496];  // A[2] 32KB each | B[2] 20KB each
  char* bufA0 = smem;
  char* bufA1 = smem + 32768;
  char* bufB0 = smem + 65536;
  char* bufB1 = smem + 86016;

  const int tid  = threadIdx.x;
  const int lane = tid & 63;
  const int wv   = tid >> 6;
  const int wm   = (wv >> 1) * 64;      // 4 m-waves
  const int wn   = (wv & 1) * 80;       // 2 n-waves

  const int id = blockIdx.x;
  const int kz = id & 7;
  const int r  = id >> 3;               // 0..31
  const int m0 = (r & 1) * BM;          // m fastest: W-strip sharers same XCD
  const int n0 = (r >> 1) * BN;
  const int kbase = kz * KCH;

  f32x4 acc[4][5] = {};

  // A gll: chunk u = j*512 + tid -> row = j*64 + (tid>>3), c8 = tid&7.
  // LDS[row][c8] holds A[row][c8 ^ (row&7)] (pre-swizzled global source).
  const int arow0 = tid >> 3;
  const int ac8   = (tid & 7) ^ (arow0 & 7);
  const unsigned short* asrc = Abf + (size_t)(m0 + arow0) * K_DIM + ac8 * 8;
  const int adst = tid * 16;

  auto stageA = [&](char* dst, int k0){
    #pragma unroll
    for (int j = 0; j < 4; ++j){
      __builtin_amdgcn_global_load_lds(
        (const __attribute__((address_space(1))) void*)(asrc + (size_t)j * 64 * K_DIM + k0),
        (__attribute__((address_space(3))) void*)(dst + j * 8192 + adst),
        16, 0, 0);
    }
  };

  // B staging: 160 rows x 16 float4 = 2560 chunks; thread handles u = j*512+tid
  const float* bsrcs[5];
  int boff[5];
  #pragma unroll
  for (int j = 0; j < 5; ++j){
    int u = j * 512 + tid;
    int brow = u >> 4;            // 0..159
    int bc4  = u & 15;
    bsrcs[j] = W + (size_t)(n0 + brow) * K_DIM + kbase + bc4 * 4;
    boff[j]  = brow * 128 + ((bc4 * 8) ^ ((brow & 7) << 4));
  }

  auto loadB = [&](int kt, float4* rr){
    #pragma unroll
    for (int j = 0; j < 5; ++j) rr[j] = *(const float4*)(bsrcs[j] + kt * BK);
  };
  auto writeB = [&](char* dst, const float4* rr){
    #pragma unroll
    for (int j = 0; j < 5; ++j){
      uint2 u;
      u.x = bfpack2(rr[j].x, rr[j].y);
      u.y = bfpack2(rr[j].z, rr[j].w);
      *(uint2*)(dst + boff[j]) = u;
    }
  };

  auto compute = [&](const char* A_, const char* B_){
    #pragma unroll
    for (int kk = 0; kk < 2; ++kk){
      bf16x8 af[4], bfv[5];
      const int kbyte = kk * 64 + (lane >> 4) * 16;
      #pragma unroll
      for (int i = 0; i < 4; ++i){
        int row = wm + i * 16 + (lane & 15);
        af[i] = *(const bf16x8*)(A_ + row * 128 + (kbyte ^ ((row & 7) << 4)));
      }
      #pragma unroll
      for (int j = 0; j < 5; ++j){
        int rowb = wn + j * 16 + (lane & 15);
        bfv[j] = *(const bf16x8*)(B_ + rowb * 128 + (kbyte ^ ((rowb & 7) << 4)));
      }
      #pragma unroll
      for (int i = 0; i < 4; ++i)
        #pragma unroll
        for (int j = 0; j < 5; ++j)
          acc[i][j] = __builtin_amdgcn_mfma_f32_16x16x32_bf16(af[i], bfv[j], acc[i][j], 0, 0, 0);
    }
  };

  float4 rbC[5], rbN[5];
  // prologue: publish A(0),B(0); B(1) in rbC
  loadB(0, rbC);
  writeB(bufB0, rbC);
  loadB(1, rbC);
  stageA(bufA0, kbase);
  __syncthreads();

  // BODY(t): stage A(t+1) [gll], load B(t+2) regs, compute(t), sync (drains all),
  // write B(t+1) to LDS, sync (publish).
  #define BODY(T, RC, RN)                                       \
    do {                                                        \
      char* An = ((T) & 1) ? bufA0 : bufA1;                     \
      char* Ac = ((T) & 1) ? bufA1 : bufA0;                     \
      char* Bc = ((T) & 1) ? bufB1 : bufB0;                     \
      char* Bn = ((T) & 1) ? bufB0 : bufB1;                     \
      if ((T) + 1 < NT) stageA(An, kbase + ((T) + 1) * BK);     \
      if ((T) + 2 < NT) loadB((T) + 2, RN);                     \
      compute(Ac, Bc);                                          \
      __syncthreads();                                          \
      if ((T) + 1 < NT) writeB(Bn, RC);                         \
      __syncthreads();                                          \
    } while (0)

  for (int t = 0; t < NT; t += 2){
    BODY(t, rbC, rbN);
    BODY(t + 1, rbN, rbC);
  }
  #undef BODY

  if (mode == 0){
    float* P = outp + (size_t)kz * M_DIM * N_DIM;
    #pragma unroll
    for (int i = 0; i < 4; ++i){
      int rbase = m0 + wm + i * 16 + (lane >> 4) * 4;
      #pragma unroll
      for (int j = 0; j < 5; ++j){
        int col = n0 + wn + j * 16 + (lane & 15);
        #pragma unroll
        for (int r2 = 0; r2 < 4; ++r2)
          P[(size_t)(rbase + r2) * N_DIM + col] = acc[i][j][r2];
      }
    }
  } else {
    #pragma unroll
    for (int i = 0; i < 4; ++i){
      int rbase = m0 + wm + i * 16 + (lane >> 4) * 4;
      #pragma unroll
      for (int j = 0; j < 5; ++j){
        int col = n0 + wn + j * 16 + (lane & 15);
        #pragma unroll
        for (int r2 = 0; r2 < 4; ++r2)
          atomicAdd(&outp[(size_t)(rbase + r2) * N_DIM + col], acc[i][j][r2]);
      }
    }
  }
}

// K5a: out[m,n] = gates[m] * (sum_z partial[z,m,n] + bias[n])
__global__ __launch_bounds__(256)
void reduce_kernel(const float* __restrict__ part, const float* __restrict__ gates,
                   const float* __restrict__ bias, float* __restrict__ out, int ksplit)
{
  int i4 = blockIdx.x * 256 + threadIdx.x;
  if (i4 >= M_DIM * N_DIM / 4) return;
  size_t off = (size_t)i4 * 4;
  int m = (int)(off / N_DIM);
  int n = (int)(off % N_DIM);
  float sx = 0.f, sy = 0.f, sz = 0.f, sw = 0.f;
  for (int z = 0; z < ksplit; ++z){
    float4 p = *(const float4*)(part + (size_t)z * M_DIM * N_DIM + off);
    sx += p.x; sy += p.y; sz += p.z; sw += p.w;
  }
  float4 bv = *(const float4*)(bias + n);
  float g = gates[m];
  float4 o;
  o.x = g * (sx + bv.x); o.y = g * (sy + bv.y);
  o.z = g * (sz + bv.z); o.w = g * (sw + bv.w);
  *(float4*)(out + off) = o;
}

// K5b: finalize after atomic accumulation
__global__ __launch_bounds__(256)
void finalize_kernel(float* __restrict__ out, const float* __restrict__ gates,
                     const float* __restrict__ bias)
{
  int i4 = blockIdx.x * 256 + threadIdx.x;
  if (i4 >= M_DIM * N_DIM / 4) return;
  size_t off = (size_t)i4 * 4;
  int m = (int)(off / N_DIM);
  int n = (int)(off % N_DIM);
  float4 o = *(const float4*)(out + off);
  float4 bv = *(const float4*)(bias + n);
  float g = gates[m];
  o.x = g * (o.x + bv.x); o.y = g * (o.y + bv.y);
  o.z = g * (o.z + bv.z); o.w = g * (o.w + bv.w);
  *(float4*)(out + off) = o;
}

extern "C" void kernel_launch(void* const* d_in, const int* in_sizes, int n_in,
                              void* d_out, int out_size, void* d_ws, size_t ws_size,
                              hipStream_t stream)
{
  const float* input   = (const float*)d_in[0];
  const float* aw      = (const float*)d_in[2];
  const float* conv1_w = (const float*)d_in[3];
  const float* conv1_b = (const float*)d_in[4];
  const float* G3_w    = (const float*)d_in[5];
  const float* G3_b    = (const float*)d_in[6];
  const float* ffnn1_w = (const float*)d_in[7];
  const float* ffnn1_b = (const float*)d_in[8];
  float* out = (float*)d_out;

  float* wsf    = (float*)d_ws;
  float* w_mean = wsf;               // 16384 f
  float* pooled = wsf + 16384;       // 512 f
  float* gates  = wsf + 16896;       // 512 f
  float* b_mean = wsf + 17408;       // 64 f pad
  unsigned short* xbf = (unsigned short*)(wsf + 17472);        // 16 MB
  float* partial = wsf + 17472 + (size_t)M_DIM * K_DIM / 2;    // 8 * 512*2560 f

  const size_t need_det = ((size_t)17472 + (size_t)M_DIM * K_DIM / 2
                           + (size_t)KSPLIT * M_DIM * N_DIM) * 4;   // ~58.8MB

  prep_kernel<<<64, 256, 0, stream>>>(conv1_w, conv1_b, w_mean, b_mean);
  pooled_kernel<<<512, 256, 0, stream>>>(input, w_mean, b_mean, pooled, xbf);
  gates_kernel<<<1, 512, 0, stream>>>(pooled, ffnn1_w, ffnn1_b, aw, gates);

  const int n4 = M_DIM * N_DIM / 4;
  const int grid = (M_DIM / BM) * (N_DIM / BN) * KSPLIT;   // 2*16*8 = 256
  if (ws_size >= need_det){
    gemm_kernel<<<grid, 512, 0, stream>>>(xbf, G3_w, partial, 0);
    reduce_kernel<<<(n4 + 255) / 256, 256, 0, stream>>>(partial, gates, G3_b, out, KSPLIT);
  } else {
    hipMemsetAsync(d_out, 0, (size_t)out_size * sizeof(float), stream);
    gemm_kernel<<<grid, 512, 0, stream>>>(xbf, G3_w, out, 2);
    finalize_kernel<<<(n4 + 255) / 256, 256, 0, stream>>>(out, gates, G3_b);
  }
}